// Round 1
// baseline (325.409 us; speedup 1.0000x reference)
//
#include <hip/hip_runtime.h>
#include <stdint.h>

#define CIN 256
#define HW  3136   // 56*56
#define HW4 784    // float4 per channel plane
#define NB  32
#define NHO 28
#define NWO 28

// ---------------- K1a: per-channel partial sum / sumsq (fp64) ----------------
__global__ void k_stats_partial(const float* __restrict__ x, double* __restrict__ part) {
    int blk = blockIdx.x;          // c*8 + chunk
    int c = blk >> 3;
    int chunk = blk & 7;
    int tid = threadIdx.x;
    double s = 0.0, sq = 0.0;
    for (int bq = 0; bq < 4; ++bq) {
        int b = chunk * 4 + bq;
        const float4* base = (const float4*)x + (size_t)(b * CIN + c) * HW4;
        for (int i = tid; i < HW4; i += 256) {
            float4 v = base[i];
            double a0 = v.x, a1 = v.y, a2 = v.z, a3 = v.w;
            s  += (a0 + a1) + (a2 + a3);
            sq += (a0*a0 + a1*a1) + (a2*a2 + a3*a3);
        }
    }
    __shared__ double ls[256], lq[256];
    ls[tid] = s; lq[tid] = sq;
    __syncthreads();
    for (int off = 128; off > 0; off >>= 1) {
        if (tid < off) { ls[tid] += ls[tid+off]; lq[tid] += lq[tid+off]; }
        __syncthreads();
    }
    if (tid == 0) {
        part[blk*2]   = ls[0];
        part[blk*2+1] = lq[0];
    }
}

// ---------------- K1b: finalize per-channel mean / scale (fp64) ----------------
__global__ void k_stats_final(const double* __restrict__ part,
                              const float* __restrict__ gamma, const float* __restrict__ beta,
                              double* __restrict__ mean_d, double* __restrict__ sg_d,
                              double* __restrict__ beta_d) {
    int c = threadIdx.x;
    double s = 0.0, sq = 0.0;
    for (int k = 0; k < 8; ++k) {
        s  += part[(c*8+k)*2];
        sq += part[(c*8+k)*2+1];
    }
    const double n = 100352.0;     // 32*3136
    double mean = s / n;
    double var  = sq / n - mean*mean;
    if (var < 0.0) var = 0.0;
    double invstd = 1.0 / sqrt(var + 1e-5);
    mean_d[c] = mean;
    sg_d[c]   = invstd * (double)gamma[c];
    beta_d[c] = (double)beta[c];
}

// ---------------- K0: pack weight sign bits (ballot over c-lanes) ----------------
__global__ void k_pack_w(const float* __restrict__ w1, const float* __restrict__ w2,
                         unsigned long long* __restrict__ wp) {
    int p = blockIdx.x;
    const float* w = p ? w2 : w1;
    int tid = threadIdx.x;
    int wv = tid >> 6, l = tid & 63;
    for (int o = 0; o < 256; ++o) {
        float v = w[o*256 + wv*64 + l];               // coalesced within wave
        unsigned long long m = __ballot(v >= 0.0f);
        if (l == 0) wp[p*1024 + o*4 + wv] = m;
    }
}

// ---------------- K2: binarize + pack activations ----------------
// Block = (b, ho) row-pair. Phase A: coalesced float4 loads -> fp64 predicate ->
// LDS bytes (row stride 116B = 29 words, conflict-free). Phase B: ballot over
// c-lanes -> u64 bitplanes ap[p][b][ho][wo][g].
__global__ void k_binpack(const float* __restrict__ x,
                          const double* __restrict__ mean_d, const double* __restrict__ sg_d,
                          const double* __restrict__ beta_d,
                          unsigned long long* __restrict__ ap) {
    __shared__ double smean[256], ssg[256], sbeta[256];
    __shared__ unsigned char pred[256*116];
    int blk = blockIdx.x;
    int b = blk / NHO, ho = blk % NHO;
    int tid = threadIdx.x;
    smean[tid] = mean_d[tid]; ssg[tid] = sg_d[tid]; sbeta[tid] = beta_d[tid];
    __syncthreads();

    uint32_t* pred32 = (uint32_t*)pred;
    #pragma unroll 4
    for (int k = 0; k < 28; ++k) {
        int i4 = tid + k*256;                 // 0..7167 over (c, r4)
        int c  = i4 / 28;
        int r4 = i4 - c*28;                   // float4 index within the 112-float row pair
        float4 v = ((const float4*)x)[(size_t)(b*CIN + c)*HW4 + ho*28 + r4];
        double m = smean[c], sg = ssg[c], bt = sbeta[c];
        uint32_t bits = 0;
        bits |= (((double)v.x - m)*sg + bt >= 0.0) ? 0x00000001u : 0u;
        bits |= (((double)v.y - m)*sg + bt >= 0.0) ? 0x00000100u : 0u;
        bits |= (((double)v.z - m)*sg + bt >= 0.0) ? 0x00010000u : 0u;
        bits |= (((double)v.w - m)*sg + bt >= 0.0) ? 0x01000000u : 0u;
        pred32[c*29 + r4] = bits;             // 116-byte row stride, word-aligned
    }
    __syncthreads();

    int g = tid >> 6, l = tid & 63;           // wave g owns channel group g
    int c = g*64 + l;
    for (int p = 0; p < 2; ++p) {
        for (int wo = 0; wo < NWO; ++wo) {
            // r = p*56 + (2*wo + p) within the 112-float row pair
            unsigned char pr = pred[c*116 + p*57 + 2*wo];
            unsigned long long mask = __ballot(pr != 0);
            if (l == 0)
                ap[(size_t)(((p*NB + b)*NHO + ho)*NWO + wo)*4 + g] = mask;
        }
    }
}

// ---------------- K3: popcount GEMM + write ----------------
// Block = (b, ho). Weights staged in LDS (broadcast reads). Lanes: wi = wo,
// o_sub selects 1 of 8 output rows per 32-lane group -> 28-float coalesced rows.
__global__ void k_bingemm(const unsigned long long* __restrict__ ap,
                          const unsigned long long* __restrict__ wp,
                          float* __restrict__ out) {
    __shared__ unsigned long long wl[2048];
    int tid = threadIdx.x;
    for (int k = tid; k < 2048; k += 256) wl[k] = wp[k];
    int blk = blockIdx.x;
    int b = blk / NHO, ho = blk % NHO;
    int o_sub = tid >> 5, wi = tid & 31;
    bool act = wi < NWO;
    unsigned long long a0[2][4];
    if (act) {
        for (int p = 0; p < 2; ++p)
            #pragma unroll
            for (int j = 0; j < 4; ++j)
                a0[p][j] = ap[(size_t)(((p*NB + b)*NHO + ho)*NWO + wi)*4 + j];
    }
    __syncthreads();
    if (!act) return;
    for (int p = 0; p < 2; ++p) {
        size_t outbase = ((size_t)(b*512 + p*256) * 784) + (size_t)ho*NWO + wi;
        #pragma unroll 4
        for (int og = 0; og < 32; ++og) {
            int o = og*8 + o_sub;
            const unsigned long long* w = &wl[p*1024 + o*4];
            int d = __popcll(a0[p][0]^w[0]) + __popcll(a0[p][1]^w[1])
                  + __popcll(a0[p][2]^w[2]) + __popcll(a0[p][3]^w[3]);
            out[outbase + (size_t)o*784] = (float)(256 - 2*d);
        }
    }
}

extern "C" void kernel_launch(void* const* d_in, const int* in_sizes, int n_in,
                              void* d_out, int out_size, void* d_ws, size_t ws_size,
                              hipStream_t stream) {
    const float* x     = (const float*)d_in[0];
    const float* gamma = (const float*)d_in[1];
    const float* beta  = (const float*)d_in[2];
    const float* w1    = (const float*)d_in[3];
    const float* w2    = (const float*)d_in[4];
    float* out = (float*)d_out;

    char* ws = (char*)d_ws;
    double* part   = (double*)ws;                        // 2048*2 doubles = 32 KB
    double* mean_d = (double*)(ws + 32768);              // 2 KB
    double* sg_d   = (double*)(ws + 34816);              // 2 KB
    double* beta_d = (double*)(ws + 36864);              // 2 KB
    unsigned long long* wp = (unsigned long long*)(ws + 40960);   // 16 KB
    unsigned long long* ap = (unsigned long long*)(ws + 57344);   // 1.6 MB

    k_stats_partial<<<2048, 256, 0, stream>>>(x, part);
    k_pack_w<<<2, 256, 0, stream>>>(w1, w2, wp);
    k_stats_final<<<1, 256, 0, stream>>>(part, gamma, beta, mean_d, sg_d, beta_d);
    k_binpack<<<NB*NHO, 256, 0, stream>>>(x, mean_d, sg_d, beta_d, ap);
    k_bingemm<<<NB*NHO, 256, 0, stream>>>(ap, wp, out);
}

// Round 2
// 216.422 us; speedup vs baseline: 1.5036x; 1.5036x over previous
//
#include <hip/hip_runtime.h>
#include <stdint.h>

#define CIN 256
#define HW  3136   // 56*56
#define HW4 784    // float4 per channel plane
#define NB  32
#define NHO 28
#define NWO 28

// ---------------- K1a: per-channel partial sum / sumsq (fp64) ----------------
__global__ void k_stats_partial(const float* __restrict__ x, double* __restrict__ part) {
    int blk = blockIdx.x;          // c*8 + chunk
    int c = blk >> 3;
    int chunk = blk & 7;
    int tid = threadIdx.x;
    double s = 0.0, sq = 0.0;
    for (int bq = 0; bq < 4; ++bq) {
        int b = chunk * 4 + bq;
        const float4* base = (const float4*)x + (size_t)(b * CIN + c) * HW4;
        for (int i = tid; i < HW4; i += 256) {
            float4 v = base[i];
            double a0 = v.x, a1 = v.y, a2 = v.z, a3 = v.w;
            s  += (a0 + a1) + (a2 + a3);
            sq += (a0*a0 + a1*a1) + (a2*a2 + a3*a3);
        }
    }
    __shared__ double ls[256], lq[256];
    ls[tid] = s; lq[tid] = sq;
    __syncthreads();
    for (int off = 128; off > 0; off >>= 1) {
        if (tid < off) { ls[tid] += ls[tid+off]; lq[tid] += lq[tid+off]; }
        __syncthreads();
    }
    if (tid == 0) {
        part[blk*2]   = ls[0];
        part[blk*2+1] = lq[0];
    }
}

// ---------------- K1b: finalize stats (block 512) + pack weight bits (blocks 0..511) ----
// Weight packing: one wave per (p, o, wv) — 2048 waves, fully latency-overlapped.
__global__ void k_finalize(const double* __restrict__ part,
                           const float* __restrict__ gamma, const float* __restrict__ beta,
                           const float* __restrict__ w1, const float* __restrict__ w2,
                           double* __restrict__ mean_d, double* __restrict__ sg_d,
                           double* __restrict__ beta_d,
                           unsigned long long* __restrict__ wp) {
    int blk = blockIdx.x;
    int tid = threadIdx.x;
    if (blk == 512) {
        int c = tid;
        double s = 0.0, sq = 0.0;
        for (int k = 0; k < 8; ++k) {
            s  += part[(c*8+k)*2];
            sq += part[(c*8+k)*2+1];
        }
        const double n = 100352.0;     // 32*3136
        double mean = s / n;
        double var  = sq / n - mean*mean;
        if (var < 0.0) var = 0.0;
        double invstd = 1.0 / sqrt(var + 1e-5);
        mean_d[c] = mean;
        sg_d[c]   = invstd * (double)gamma[c];
        beta_d[c] = (double)beta[c];
    } else {
        int wave = tid >> 6, l = tid & 63;
        int w_idx = blk * 4 + wave;            // [0,2048) == p*1024 + o*4 + wv
        int p = w_idx >> 10;
        int rem = w_idx & 1023;
        int o = rem >> 2, wv = rem & 3;
        const float* w = p ? w2 : w1;
        float v = w[o*256 + wv*64 + l];
        unsigned long long m = __ballot(v >= 0.0f);
        if (l == 0) wp[w_idx] = m;
    }
}

// ---------------- K2: binarize + pack activations ----------------
// Block = (b, ho) row-pair. Phase A: coalesced float4 loads -> fp64 predicate ->
// LDS bytes (row stride 116B = 29 words, conflict-free). Phase B: ballot over
// c-lanes -> u64 bitplanes ap[p][b][ho][wo][g].
__global__ void k_binpack(const float* __restrict__ x,
                          const double* __restrict__ mean_d, const double* __restrict__ sg_d,
                          const double* __restrict__ beta_d,
                          unsigned long long* __restrict__ ap) {
    __shared__ double smean[256], ssg[256], sbeta[256];
    __shared__ unsigned char pred[256*116];
    int blk = blockIdx.x;
    int b = blk / NHO, ho = blk % NHO;
    int tid = threadIdx.x;
    smean[tid] = mean_d[tid]; ssg[tid] = sg_d[tid]; sbeta[tid] = beta_d[tid];
    __syncthreads();

    uint32_t* pred32 = (uint32_t*)pred;
    #pragma unroll 4
    for (int k = 0; k < 28; ++k) {
        int i4 = tid + k*256;                 // 0..7167 over (c, r4)
        int c  = i4 / 28;
        int r4 = i4 - c*28;                   // float4 index within the 112-float row pair
        float4 v = ((const float4*)x)[(size_t)(b*CIN + c)*HW4 + ho*28 + r4];
        double m = smean[c], sg = ssg[c], bt = sbeta[c];
        uint32_t bits = 0;
        bits |= (((double)v.x - m)*sg + bt >= 0.0) ? 0x00000001u : 0u;
        bits |= (((double)v.y - m)*sg + bt >= 0.0) ? 0x00000100u : 0u;
        bits |= (((double)v.z - m)*sg + bt >= 0.0) ? 0x00010000u : 0u;
        bits |= (((double)v.w - m)*sg + bt >= 0.0) ? 0x01000000u : 0u;
        pred32[c*29 + r4] = bits;             // 116-byte row stride, word-aligned
    }
    __syncthreads();

    int g = tid >> 6, l = tid & 63;           // wave g owns channel group g
    int c = g*64 + l;
    for (int p = 0; p < 2; ++p) {
        for (int wo = 0; wo < NWO; ++wo) {
            // r = p*56 + (2*wo + p) within the 112-float row pair
            unsigned char pr = pred[c*116 + p*57 + 2*wo];
            unsigned long long mask = __ballot(pr != 0);
            if (l == 0)
                ap[(size_t)(((p*NB + b)*NHO + ho)*NWO + wo)*4 + g] = mask;
        }
    }
}

// ---------------- K3: popcount GEMM + write ----------------
// Block = (b, ho). Weights staged in LDS (broadcast reads). Lanes: wi = wo,
// o_sub selects 1 of 8 output rows per 32-lane group -> 28-float coalesced rows.
__global__ void k_bingemm(const unsigned long long* __restrict__ ap,
                          const unsigned long long* __restrict__ wp,
                          float* __restrict__ out) {
    __shared__ unsigned long long wl[2048];
    int tid = threadIdx.x;
    for (int k = tid; k < 2048; k += 256) wl[k] = wp[k];
    int blk = blockIdx.x;
    int b = blk / NHO, ho = blk % NHO;
    int o_sub = tid >> 5, wi = tid & 31;
    bool act = wi < NWO;
    unsigned long long a0[2][4];
    if (act) {
        for (int p = 0; p < 2; ++p)
            #pragma unroll
            for (int j = 0; j < 4; ++j)
                a0[p][j] = ap[(size_t)(((p*NB + b)*NHO + ho)*NWO + wi)*4 + j];
    }
    __syncthreads();
    if (!act) return;
    for (int p = 0; p < 2; ++p) {
        size_t outbase = ((size_t)(b*512 + p*256) * 784) + (size_t)ho*NWO + wi;
        #pragma unroll 4
        for (int og = 0; og < 32; ++og) {
            int o = og*8 + o_sub;
            const unsigned long long* w = &wl[p*1024 + o*4];
            int d = __popcll(a0[p][0]^w[0]) + __popcll(a0[p][1]^w[1])
                  + __popcll(a0[p][2]^w[2]) + __popcll(a0[p][3]^w[3]);
            out[outbase + (size_t)o*784] = (float)(256 - 2*d);
        }
    }
}

extern "C" void kernel_launch(void* const* d_in, const int* in_sizes, int n_in,
                              void* d_out, int out_size, void* d_ws, size_t ws_size,
                              hipStream_t stream) {
    const float* x     = (const float*)d_in[0];
    const float* gamma = (const float*)d_in[1];
    const float* beta  = (const float*)d_in[2];
    const float* w1    = (const float*)d_in[3];
    const float* w2    = (const float*)d_in[4];
    float* out = (float*)d_out;

    char* ws = (char*)d_ws;
    double* part   = (double*)ws;                        // 2048*2 doubles = 32 KB
    double* mean_d = (double*)(ws + 32768);              // 2 KB
    double* sg_d   = (double*)(ws + 34816);              // 2 KB
    double* beta_d = (double*)(ws + 36864);              // 2 KB
    unsigned long long* wp = (unsigned long long*)(ws + 40960);   // 16 KB
    unsigned long long* ap = (unsigned long long*)(ws + 57344);   // 1.6 MB

    k_stats_partial<<<2048, 256, 0, stream>>>(x, part);
    k_finalize<<<513, 256, 0, stream>>>(part, gamma, beta, w1, w2, mean_d, sg_d, beta_d, wp);
    k_binpack<<<NB*NHO, 256, 0, stream>>>(x, mean_d, sg_d, beta_d, ap);
    k_bingemm<<<NB*NHO, 256, 0, stream>>>(ap, wp, out);
}

// Round 4
// 205.951 us; speedup vs baseline: 1.5800x; 1.0508x over previous
//
#include <hip/hip_runtime.h>
#include <stdint.h>

#define CIN 256
#define HW4 784    // float4 per channel plane (56*56/4)
#define NB  32
#define NHO 28
#define NWO 28

// ---------------- K1: stats partials (blocks 0..2047) + weight packing (2048..2175) ----
__global__ __launch_bounds__(256) void k_stage1(const float* __restrict__ x,
                          const float* __restrict__ w1, const float* __restrict__ w2,
                          double* __restrict__ part, unsigned long long* __restrict__ wp) {
    int blk = blockIdx.x;
    int tid = threadIdx.x;
    if (blk < 2048) {
        int c = blk >> 3, chunk = blk & 7;
        double s = 0.0, sq = 0.0;
        for (int bq = 0; bq < 4; ++bq) {
            int b = chunk * 4 + bq;
            const float4* base = (const float4*)x + (size_t)(b * CIN + c) * HW4;
            for (int i = tid; i < HW4; i += 256) {
                float4 v = base[i];
                double a0 = v.x, a1 = v.y, a2 = v.z, a3 = v.w;
                s  += (a0 + a1) + (a2 + a3);
                sq += (a0*a0 + a1*a1) + (a2*a2 + a3*a3);
            }
        }
        __shared__ double ls[256], lq[256];
        ls[tid] = s; lq[tid] = sq;
        __syncthreads();
        for (int off = 128; off > 0; off >>= 1) {
            if (tid < off) { ls[tid] += ls[tid+off]; lq[tid] += lq[tid+off]; }
            __syncthreads();
        }
        if (tid == 0) {   // transposed layout [chunk][c] for coalesced re-read
            part[(chunk*256 + c)*2]   = ls[0];
            part[(chunk*256 + c)*2+1] = lq[0];
        }
    } else {
        // weight packing: 2048 wave-tasks over 128 blocks * 4 waves * 4 tasks
        int wave = tid >> 6, l = tid & 63;
        int baseTask = ((blk - 2048)*4 + wave)*4;
        #pragma unroll
        for (int t = 0; t < 4; ++t) {
            int w_idx = baseTask + t;            // p*1024 + o*4 + wv
            int p = w_idx >> 10, rem = w_idx & 1023;
            int o = rem >> 2, wv = rem & 3;
            const float* w = p ? w2 : w1;
            float v = w[o*256 + wv*64 + l];
            unsigned long long m = __ballot(v >= 0.0f);
            if (l == 0) wp[w_idx] = m;
        }
    }
}

// ---------------- K2: fused finalize + binarize + pack + popcount GEMM ----------------
// Block = (b, ho). LDS: stats 6KB + pred 15KB + weights 16KB + apl 1.75KB = 38.8KB
// -> 4 blocks/CU. Only the 2-of-4 pixels each phase consumes are predicated.
__global__ __launch_bounds__(256) void k_fused(const float* __restrict__ x,
    const double* __restrict__ part, const float* __restrict__ gamma,
    const float* __restrict__ beta, const unsigned long long* __restrict__ wp,
    float* __restrict__ out) {
    __shared__ double sm[256], ssg[256], sbt[256];
    __shared__ unsigned char pred[256*60];       // 28B phase0 + 28B phase1, stride 60
    __shared__ unsigned long long wl[2048];
    __shared__ unsigned long long apl[224];      // [p][wo][g]
    int blk = blockIdx.x;
    int b = blk / NHO, ho = blk % NHO;
    int tid = threadIdx.x;

    // stage weight bits into LDS (independent of stats)
    {
        const ulonglong2* src = (const ulonglong2*)wp;
        ulonglong2* dst = (ulonglong2*)wl;
        for (int k = tid; k < 1024; k += 256) dst[k] = src[k];
    }
    // per-channel stats finalize from partials (coalesced: lane stride 16B)
    {
        int c = tid;
        double s = 0.0, sq = 0.0;
        for (int k = 0; k < 8; ++k) {
            s  += part[(k*256 + c)*2];
            sq += part[(k*256 + c)*2+1];
        }
        const double n = 100352.0;               // 32*3136
        double mean = s / n;
        double var  = sq / n - mean*mean;
        if (var < 0.0) var = 0.0;
        double invstd = 1.0 / sqrt(var + 1e-5);
        sm[c] = mean; ssg[c] = invstd * (double)gamma[c]; sbt[c] = (double)beta[c];
    }
    __syncthreads();

    // predicate phase: 7168 float4 over (c, r4); keep 2 of 4 pixels each
    #pragma unroll 4
    for (int k = 0; k < 28; ++k) {
        int i4 = tid + k*256;
        int c = i4 / 28, r4 = i4 - c*28;         // r4<14: row 2ho; r4>=14: row 2ho+1
        float4 v = ((const float4*)x)[(size_t)(b*CIN + c)*HW4 + ho*28 + r4];
        double m = sm[c], sg = ssg[c], bt = sbt[c];
        unsigned short bits; int off;
        if (r4 < 14) {   // even row -> even cols: elems x (col 4r4), z (col 4r4+2)
            bits  = (((double)v.x - m)*sg + bt >= 0.0) ? 1u : 0u;
            bits |= (((double)v.z - m)*sg + bt >= 0.0) ? 0x100u : 0u;
            off = c*60 + 2*r4;                   // byte j of phase0 = wo j
        } else {         // odd row -> odd cols: elems y (col 4r'+1), w (col 4r'+3)
            bits  = (((double)v.y - m)*sg + bt >= 0.0) ? 1u : 0u;
            bits |= (((double)v.w - m)*sg + bt >= 0.0) ? 0x100u : 0u;
            off = c*60 + 28 + 2*(r4 - 14);       // byte 28+j = phase1 wo j
        }
        *(unsigned short*)&pred[off] = bits;
    }
    __syncthreads();

    // ballot phase: wave g owns channels [64g, 64g+64); lane stride 60B -> 2-way banks (free)
    {
        int g = tid >> 6, l = tid & 63;
        int c = g*64 + l;
        for (int p = 0; p < 2; ++p)
            for (int wo = 0; wo < NWO; ++wo) {
                unsigned char pr = pred[c*60 + p*28 + wo];
                unsigned long long mask = __ballot(pr != 0);
                if (l == 0) apl[p*112 + wo*4 + g] = mask;
            }
    }
    __syncthreads();

    // popcount GEMM: o_sub picks 1 of 8 output rows per 32-lane group -> coalesced 28-float rows
    int o_sub = tid >> 5, wi = tid & 31;
    if (wi >= NWO) return;
    unsigned long long a0[2][4];
    for (int p = 0; p < 2; ++p)
        #pragma unroll
        for (int j = 0; j < 4; ++j) a0[p][j] = apl[p*112 + wi*4 + j];
    for (int p = 0; p < 2; ++p) {
        size_t outbase = ((size_t)(b*512 + p*256))*784 + (size_t)ho*NWO + wi;
        #pragma unroll 4
        for (int og = 0; og < 32; ++og) {
            int o = og*8 + o_sub;
            const unsigned long long* w = &wl[p*1024 + o*4];
            int d = __popcll(a0[p][0]^w[0]) + __popcll(a0[p][1]^w[1])
                  + __popcll(a0[p][2]^w[2]) + __popcll(a0[p][3]^w[3]);
            out[outbase + (size_t)o*784] = (float)(256 - 2*d);
        }
    }
}

extern "C" void kernel_launch(void* const* d_in, const int* in_sizes, int n_in,
                              void* d_out, int out_size, void* d_ws, size_t ws_size,
                              hipStream_t stream) {
    const float* x     = (const float*)d_in[0];
    const float* gamma = (const float*)d_in[1];
    const float* beta  = (const float*)d_in[2];
    const float* w1    = (const float*)d_in[3];
    const float* w2    = (const float*)d_in[4];
    float* out = (float*)d_out;

    char* ws = (char*)d_ws;
    double* part = (double*)ws;                               // 2048*2 doubles = 32 KB
    unsigned long long* wp = (unsigned long long*)(ws + 40960); // 16 KB

    k_stage1<<<2176, 256, 0, stream>>>(x, w1, w2, part, wp);
    k_fused<<<NB*NHO, 256, 0, stream>>>(x, part, gamma, beta, wp, out);
}